// Round 1
// baseline (713.251 us; speedup 1.0000x reference)
//
#include <hip/hip_runtime.h>

#define DIM_OUT 64
#define ALPHA 0.5f

// One thread per row. Gegenbauer recurrence fully unrolled so the i-dependent
// coefficients (2i-2+2a), (2-i-2a) and 1/i are all compile-time constants.
// Each thread writes its 64 outputs as 16 float4 stores (row-contiguous 256B).
__global__ __launch_bounds__(256) void geg_kernel(const float* __restrict__ x,
                                                  float* __restrict__ out,
                                                  int n) {
    int row = blockIdx.x * blockDim.x + threadIdx.x;
    if (row >= n) return;

    float xv = x[row];

    float prev2 = 1.0f;               // C_0
    float prev  = 2.0f * ALPHA * xv;  // C_1

    float4* outv = (float4*)(out + (size_t)row * DIM_OUT);

    float b0 = prev, b1, b2, b3;
    int lane_in4 = 1;   // resolved at compile time under full unroll
    int vec_idx  = 0;

    float buf[4];
    buf[0] = prev;
    (void)b0; (void)b1; (void)b2; (void)b3; (void)lane_in4;

    int bi = 1;
    #pragma unroll
    for (int i = 2; i <= DIM_OUT; ++i) {
        const float a   = (2.0f * (float)i - 2.0f + 2.0f * ALPHA);
        const float b   = (-(float)i + 2.0f - 2.0f * ALPHA);
        const float inv = 1.0f / (float)i;
        float ci = (a * xv * prev + b * prev2) * inv;
        prev2 = prev;
        prev  = ci;
        buf[bi] = ci;
        ++bi;
        if (bi == 4) {
            outv[vec_idx] = make_float4(buf[0], buf[1], buf[2], buf[3]);
            vec_idx++;
            bi = 0;
        }
    }
}

extern "C" void kernel_launch(void* const* d_in, const int* in_sizes, int n_in,
                              void* d_out, int out_size, void* d_ws, size_t ws_size,
                              hipStream_t stream) {
    const float* x = (const float*)d_in[0];
    float* out = (float*)d_out;
    int n = in_sizes[0];   // 2,000,000 rows (x is [n,1])

    const int block = 256;
    const int grid = (n + block - 1) / block;
    geg_kernel<<<grid, block, 0, stream>>>(x, out, n);
}